// Round 16
// baseline (286.247 us; speedup 1.0000x reference)
//
#include <hip/hip_runtime.h>

#define BATCH 16
#define CIN 512
#define NPIX 4096

typedef __attribute__((ext_vector_type(8))) short bf16x8;
typedef __attribute__((ext_vector_type(4))) float f32x4;

#define MFMA(a,b,c) __builtin_amdgcn_mfma_f32_16x16x32_bf16((a),(b),(c),0,0,0)

// async global->LDS DMA, 16B/lane, dst = wave-uniform base (+ HW lane*16)
#define GLOAD(g, l) __builtin_amdgcn_global_load_lds( \
    (const __attribute__((address_space(1))) unsigned int*)(g), \
    (__attribute__((address_space(3))) unsigned int*)(l), 16, 0, 0)

union PK  { short s[8]; bf16x8 v; };
union PK4 { short s[4]; uint2 u; };

__device__ __forceinline__ unsigned short bf16_rne(float f){
  unsigned u = __float_as_uint(f);
  return (unsigned short)((u + 0x7fffu + ((u >> 16) & 1u)) >> 16);
}
__device__ __forceinline__ void f32_split(float f, short &h, short &l){
  unsigned short hu = bf16_rne(f);
  h = (short)hu;
  float fh = __uint_as_float((unsigned)hu << 16);
  l = (short)bf16_rne(f - fh);
}
__device__ __forceinline__ void split8(float4 a, float4 b, bf16x8 &h, bf16x8 &l){
  float vv[8] = {a.x,a.y,a.z,a.w,b.x,b.y,b.z,b.w};
  PK ph, pl;
  #pragma unroll
  for (int z=0;z<8;z++){ short hh,ll; f32_split(vv[z],hh,ll); ph.s[z]=hh; pl.s[z]=ll; }
  h = ph.v; l = pl.v;
}

// ---------------- weight convert + gate-algebra precompute + ws zeroing ----------------
// WALL2 [16 kt][768 rows][32 k] bf16, chunk^(row&3) swizzle baked in:
//   rows 0-511: interleaved QK-hi (2o=Wq, 2o+1=Wk); 512-575 Ws-hi; 576-639 Ws-lo;
//   640-703 We-hi; 704-767 zero-pad.
// VV[512] = Wk^T bq + Wq^T bk (f32); DD[0] = bq.bk; BSE[128] = {bs, be}.
__global__ __launch_bounds__(256)
void k_convw(const float* __restrict__ Wq, const float* __restrict__ bq,
             const float* __restrict__ Wk, const float* __restrict__ bk,
             const float* __restrict__ Ws, const float* __restrict__ bs,
             const float* __restrict__ We, const float* __restrict__ be,
             short* __restrict__ WALL2, float* __restrict__ BSE,
             float* __restrict__ VV, float* __restrict__ DD,
             float* __restrict__ QKacc, float* __restrict__ Mb){
  int t = blockIdx.x*256 + threadIdx.x;   // t < 768*512
  if (t < 768*512){
    int r = t >> 9, k = t & 511;
    float v;
    short out;
    if (r < 512){
      v = (r & 1) ? Wk[(r>>1)*512 + k] : Wq[(r>>1)*512 + k];
      out = (short)bf16_rne(v);
    } else if (r < 576){
      short h,l; f32_split(Ws[(r-512)*512 + k], h, l); out = h;
    } else if (r < 640){
      short h,l; f32_split(Ws[(r-576)*512 + k], h, l); out = l;
    } else if (r < 704){
      out = (short)bf16_rne(We[(r-640)*512 + k]);
    } else {
      out = 0;
    }
    int kt = k >> 5, lc = (k >> 3) & 3, e = k & 7;
    int pc = lc ^ (r & 3);
    WALL2[((size_t)kt*768 + r)*32 + pc*8 + e] = out;
  }
  if (t < 128) BSE[t] = (t < 64) ? bs[t] : be[t-64];
  if (t < 512){
    float a = 0.f;
    for (int o=0;o<256;o++) a += bq[o]*Wk[o*512+t] + bk[o]*Wq[o*512+t];
    VV[t] = a;
  }
  if (t == 0){
    float a = 0.f;
    for (int o=0;o<256;o++) a += bq[o]*bk[o];
    DD[0] = a;
  }
  // zero accumulation buffers
  for (int i = t; i < BATCH*NPIX; i += 1536*256) QKacc[i] = 0.f;
  for (int i = t; i < BATCH*512*64; i += 1536*256) Mb[i] = 0.f;
}

// ---------------- x pack: XT2[b][nt 32][kt 16][128 n][32 k] bf16, swizzled ----------------
// Also folds v.x into QKacc (exact f32).
__global__ __launch_bounds__(256)
void k_stage(const float* __restrict__ x, const float* __restrict__ VV,
             short* __restrict__ XT2, float* __restrict__ QKacc){
  __shared__ float XF[64*65];
  int cb = blockIdx.x, nb = blockIdx.y, b = blockIdx.z;
  int tid = threadIdx.x;
  {
    int cc = tid >> 2, ni = (tid & 3) * 16;
    const float* xp = x + ((size_t)(b*CIN + cb*64 + cc))*NPIX + nb*64 + ni;
    #pragma unroll
    for (int u=0;u<16;u+=4){
      float4 v = *(const float4*)(xp + u);
      XF[cc*65 + ni+u+0] = v.x; XF[cc*65 + ni+u+1] = v.y;
      XF[cc*65 + ni+u+2] = v.z; XF[cc*65 + ni+u+3] = v.w;
    }
  }
  __syncthreads();
  {
    int nn = tid >> 2, cs = tid & 3;
    int nl = (nb & 1)*64 + nn, nt = nb >> 1;
    int kt = cb*2 + (cs >> 1);
    float pa = 0.f;
    PK c0, c1;
    #pragma unroll
    for (int i=0;i<8;i++){
      float f = XF[(cs*16 + i)*65 + nn];
      pa += VV[cb*64 + cs*16 + i] * f;
      c0.s[i] = (short)bf16_rne(f);
    }
    #pragma unroll
    for (int i=0;i<8;i++){
      float f = XF[(cs*16 + 8 + i)*65 + nn];
      pa += VV[cb*64 + cs*16 + 8 + i] * f;
      c1.s[i] = (short)bf16_rne(f);
    }
    short* rowb = XT2 + ((((size_t)(b*32 + nt))*16 + kt)*128 + nl)*32;
    int pc0 = ((cs & 1)*2 + 0) ^ (nl & 3);
    int pc1 = ((cs & 1)*2 + 1) ^ (nl & 3);
    *(bf16x8*)&rowb[pc0*8] = c0.v;
    *(bf16x8*)&rowb[pc1*8] = c1.v;
    pa += __shfl_xor(pa, 1);
    pa += __shfl_xor(pa, 2);
    if ((tid & 3) == 0)
      atomicAdd(&QKacc[(size_t)b*NPIX + nb*64 + nn], pa);
  }
}

// ---------------- fused gemm: all 768 A-rows, one dispatch wave ----------------
// grid (32 nt, 6 mt, 16 b), 256 thr, m97 anatomy (dbuf GLOAD A+B, acc[4][4]).
// mt 0-3: QK pair-product -> QKacc. mt 4: Qs hi|lo -> QSR (UN-gated; gate folded
// in k_M -> bit-identical QSG values). mt 5: Ke -> KET.
__global__ __launch_bounds__(256)
void k_gemm12(const short* __restrict__ WALL2, const short* __restrict__ XT2,
              const float* __restrict__ BSE,
              float* __restrict__ QKacc, float* __restrict__ QSR,
              short* __restrict__ KET){
  __shared__ __align__(16) char SMEM[32768];
  short (*As)[128*32] = (short(*)[128*32])SMEM;            // 2 x 8KB
  short (*Bs)[128*32] = (short(*)[128*32])(SMEM + 16384);  // 2 x 8KB
  __shared__ float QKp[2][2][4][16];
  int nt = blockIdx.x, mt = blockIdx.y, b = blockIdx.z;
  int tid = threadIdx.x, w = tid>>6, lane = tid&63;
  int lr = lane&15, cg = lane>>4;
  int rh = w>>1, nh = w&1;
  const char* Abase = (const char*)WALL2 + (size_t)mt*128*64;
  const char* Bbase = (const char*)XT2 + ((size_t)(b*32 + nt)*16)*8192;
  #pragma unroll
  for (int i=0;i<2;i++){
    GLOAD(Abase + (i*256+tid)*16, ((char*)&As[0][0]) + (i*256+(tid&~63))*16);
    GLOAD(Bbase + (i*256+tid)*16, ((char*)&Bs[0][0]) + (i*256+(tid&~63))*16);
  }
  f32x4 acc[4][4] = {};
  int swz = ((cg ^ (lr&3)) << 3);
  for (int kt=0; kt<16; kt++){
    int cur = kt & 1;
    __syncthreads();
    if (kt < 15){
      const char* An = Abase + (size_t)(kt+1)*768*64;
      const char* Bn = Bbase + (size_t)(kt+1)*8192;
      #pragma unroll
      for (int i=0;i<2;i++){
        GLOAD(An + (i*256+tid)*16, ((char*)&As[cur^1][0]) + (i*256+(tid&~63))*16);
        GLOAD(Bn + (i*256+tid)*16, ((char*)&Bs[cur^1][0]) + (i*256+(tid&~63))*16);
      }
    }
    bf16x8 a[4], bb[4];
    #pragma unroll
    for (int m=0;m<4;m++) a[m] = *(const bf16x8*)&As[cur][(rh*64 + m*16 + lr)*32 + swz];
    #pragma unroll
    for (int j=0;j<4;j++) bb[j] = *(const bf16x8*)&Bs[cur][(nh*64 + j*16 + lr)*32 + swz];
    #pragma unroll
    for (int m=0;m<4;m++)
      #pragma unroll
      for (int j=0;j<4;j++)
        acc[m][j] = MFMA(a[m], bb[j], acc[m][j]);
  }
  __syncthreads();                          // k-loop LDS reads done
  int rq = (lane>>4)<<2;
  if (mt < 4){
    // pair product: regs (0,1),(2,3) = consecutive rows = (Q,K) of a pair
    float p[4] = {0.f,0.f,0.f,0.f};
    #pragma unroll
    for (int m=0;m<4;m++)
      #pragma unroll
      for (int j=0;j<4;j++){
        f32x4 a4 = acc[m][j];
        p[j] += a4[0]*a4[1] + a4[2]*a4[3];
      }
    #pragma unroll
    for (int j=0;j<4;j++){ p[j] += __shfl_xor(p[j],16); p[j] += __shfl_xor(p[j],32); }
    if (lane < 16){
      #pragma unroll
      for (int j=0;j<4;j++) QKp[rh][nh][j][lane] = p[j];
    }
    __syncthreads();
    if (rh == 0 && lane < 16){
      #pragma unroll
      for (int j=0;j<4;j++){
        float v = QKp[0][nh][j][lane] + QKp[1][nh][j][lane];
        atomicAdd(&QKacc[(size_t)b*NPIX + nt*128 + nh*64 + j*16 + lane], v);
      }
    }
  } else if (mt == 4){
    // Qs: rh=1 holds lo rows -> LDS handoff; rh=0 combines + bs, writes QSR (no gate)
    float* LO = (float*)SMEM;               // [nh][o 64][nl 64] f32 = 32KB
    if (rh == 1){
      #pragma unroll
      for (int m=0;m<4;m++)
        #pragma unroll
        for (int j=0;j<4;j++)
          #pragma unroll
          for (int q=0;q<4;q++)
            LO[nh*4096 + (m*16 + rq + q)*64 + j*16 + lr] = acc[m][j][q];
    }
    __syncthreads();
    if (rh == 0){
      #pragma unroll
      for (int m=0;m<4;m++){
        int o0 = m*16 + rq;
        f32x4 bs4 = *(const f32x4*)&BSE[o0];
        #pragma unroll
        for (int j=0;j<4;j++){
          int n = nt*128 + nh*64 + j*16 + lr;
          #pragma unroll
          for (int q=0;q<4;q++)
            QSR[((size_t)(b*64) + o0 + q)*NPIX + n] =
                acc[m][j][q] + LO[nh*4096 + (o0+q)*64 + j*16 + lr] + bs4[q];
        }
      }
    }
  } else {
    // Ke: rh=0 rows are We (d 0-63); rh=1 is pad (discard)
    if (rh == 0){
      #pragma unroll
      for (int m=0;m<4;m++){
        int d0 = m*16 + rq;
        f32x4 be4 = *(const f32x4*)&BSE[64 + d0];
        #pragma unroll
        for (int j=0;j<4;j++){
          int n = nt*128 + nh*64 + j*16 + lr;
          PK4 pk;
          #pragma unroll
          for (int q=0;q<4;q++) pk.s[q] = (short)bf16_rne(acc[m][j][q] + be4[q]);
          *(uint2*)&KET[((size_t)(b*NPIX) + n)*64 + d0] = pk.u;
        }
      }
    }
  }
}

// ---------------- gate ----------------
__global__ __launch_bounds__(256)
void k_gate(const float* __restrict__ QKacc, const float* __restrict__ DD,
            float* __restrict__ GATE){
  int i = blockIdx.x*256 + threadIdx.x;
  GATE[i] = 1.f/(1.f + __expf(-(QKacc[i] + DD[0]) * (1.f/256.f)));
}

// ---------------- S[b][d] = sum_n QSR[b][d][n] * GATE[b][n] ----------------
// grid (64 d, 16 b), 256 thr; one block owns one (b,d) -> direct write, no atomics.
__global__ __launch_bounds__(256)
void k_S(const float* __restrict__ QSR, const float* __restrict__ GATE,
         float* __restrict__ S){
  __shared__ float R[4];
  int d = blockIdx.x, b = blockIdx.y;
  int tid = threadIdx.x;
  const float* qp = QSR + ((size_t)(b*64) + d)*NPIX + tid*16;
  const float* gp = GATE + (size_t)b*NPIX + tid*16;
  f32x4 a = {};
  #pragma unroll
  for (int u=0;u<4;u++){
    f32x4 q4 = *(const f32x4*)(qp + u*4);
    f32x4 g4 = *(const f32x4*)(gp + u*4);
    a += q4 * g4;
  }
  float v = a[0]+a[1]+a[2]+a[3];
  #pragma unroll
  for (int s=1;s<64;s<<=1) v += __shfl_xor(v, s);
  if ((tid & 63) == 0) R[tid>>6] = v;
  __syncthreads();
  if (tid == 0) S[b*64 + d] = R[0]+R[1]+R[2]+R[3];
}

// ---------------- M[b][512][64] += x . (QSR*g)^T over n (gate folded, reg-split) ----------------
__global__ __launch_bounds__(512)
void k_M(const float* __restrict__ x, const float* __restrict__ QSR,
         const float* __restrict__ GATE, float* __restrict__ M){
  int slab = blockIdx.x, b = blockIdx.y;   // 16 slabs x 256 n
  int tid = threadIdx.x, w = tid>>6, lane = tid&63;
  int lr = lane&15, lk8 = (lane>>4)<<3;
  f32x4 acc[4][4] = {};
  for (int kt=0; kt<8; kt++){
    int noff = slab*256 + kt*32 + lk8;
    const float* gp = GATE + (size_t)b*NPIX + noff;
    float4 g0 = *(const float4*)gp;
    float4 g1 = *(const float4*)(gp + 4);
    bf16x8 bh[4], bl[4];
    #pragma unroll
    for (int j=0;j<4;j++){
      const float* qp = QSR + ((size_t)(b*64) + j*16 + lr)*NPIX + noff;
      float4 q0 = *(const float4*)qp;
      float4 q1 = *(const float4*)(qp+4);
      q0.x *= g0.x; q0.y *= g0.y; q0.z *= g0.z; q0.w *= g0.w;
      q1.x *= g1.x; q1.y *= g1.y; q1.z *= g1.z; q1.w *= g1.w;
      split8(q0, q1, bh[j], bl[j]);
    }
    #pragma unroll
    for (int r=0;r<4;r++){
      const float* xp = x + ((size_t)(b*CIN) + w*64 + r*16 + lr)*NPIX + noff;
      bf16x8 ah, al;
      split8(*(const float4*)xp, *(const float4*)(xp+4), ah, al);
      #pragma unroll
      for (int j=0;j<4;j++){
        acc[r][j] = MFMA(al, bh[j], acc[r][j]);
        acc[r][j] = MFMA(ah, bl[j], acc[r][j]);
        acc[r][j] = MFMA(ah, bh[j], acc[r][j]);
      }
    }
  }
  int rq = (lane>>4)<<2;
  #pragma unroll
  for (int r=0;r<4;r++)
    #pragma unroll
    for (int j=0;j<4;j++)
      #pragma unroll
      for (int q=0;q<4;q++)
        atomicAdd(&M[((size_t)(b*CIN) + w*64 + r*16 + rq + q)*64 + j*16 + lr], acc[r][j][q]);
}

// ---------------- energy = Wv(f32) . M + bv*S  (VALU, exact) ----------------
__global__ __launch_bounds__(256)
void k_energy(const float* __restrict__ Wv, const float* __restrict__ bv,
              const float* __restrict__ M, const float* __restrict__ S,
              float* __restrict__ EN){
  __shared__ __align__(16) float ML[128*68];
  int cch = blockIdx.x, b = blockIdx.y;
  int tid = threadIdx.x;
  int d4 = tid & 15, ci = tid >> 4;
  f32x4 acc[2] = {};
  for (int kt=0; kt<4; kt++){
    __syncthreads();
    for (int i = tid; i < 2048; i += 256){
      int k = i >> 4, c4 = (i & 15) * 4;
      *(float4*)&ML[k*68 + c4] = *(const float4*)&M[((size_t)(b*CIN) + kt*128 + k)*64 + c4];
    }
    __syncthreads();
    #pragma unroll
    for (int m=0;m<2;m++){
      int c = cch*32 + ci + 16*m;
      const float* wvp = Wv + (size_t)c*512 + kt*128;
      for (int k4=0;k4<32;k4++){
        float4 wv4 = *(const float4*)(wvp + k4*4);
        f32x4 m0 = *(const f32x4*)&ML[(k4*4+0)*68 + d4*4];
        f32x4 m1 = *(const f32x4*)&ML[(k4*4+1)*68 + d4*4];
        f32x4 m2 = *(const f32x4*)&ML[(k4*4+2)*68 + d4*4];
        f32x4 m3 = *(const f32x4*)&ML[(k4*4+3)*68 + d4*4];
        acc[m] += m0*wv4.x + m1*wv4.y + m2*wv4.z + m3*wv4.w;
      }
    }
  }
  f32x4 s4 = *(const f32x4*)&S[b*64 + d4*4];
  #pragma unroll
  for (int m=0;m<2;m++){
    int c = cch*32 + ci + 16*m;
    f32x4 r = acc[m] + s4*bv[c];
    *(f32x4*)&EN[((size_t)(b*CIN) + c)*64 + d4*4] = r;
  }
}

// ---------------- softmax over d=64 ----------------
__global__ __launch_bounds__(256)
void k_softmax(const float* __restrict__ EN, short* __restrict__ ATT){
  int row = blockIdx.x*4 + (threadIdx.x>>6);
  int lane = threadIdx.x & 63;
  float v = EN[(size_t)row*64 + lane];
  float m = v;
  #pragma unroll
  for (int s=1;s<64;s<<=1) m = fmaxf(m, __shfl_xor(m, s));
  float e = __expf(v - m);
  float sum = e;
  #pragma unroll
  for (int s=1;s<64;s<<=1) sum += __shfl_xor(sum, s);
  ATT[(size_t)row*64 + lane] = (short)bf16_rne(e / sum);
}

// ---------------- out = x + attn . Ke (LDS-transposed epilogue: 256B granules) ----------------
__global__ __launch_bounds__(512)
void k_out(const float* __restrict__ x, const short* __restrict__ ATT,
           const short* __restrict__ KET, float* __restrict__ out){
  __shared__ __align__(16) float CT[256*66];   // 67.6 KB, stride 66 breaks conflicts
  int nt = blockIdx.x, b = blockIdx.y;
  int n0 = nt*64;
  int tid = threadIdx.x, w = tid>>6, lane = tid&63;
  int lr = lane&15, lk = (lane>>4)<<3;
  f32x4 acc[4][4] = {};
  #pragma unroll
  for (int kt=0; kt<2; kt++){
    bf16x8 bb[4];
    #pragma unroll
    for (int j=0;j<4;j++)
      bb[j] = *(const bf16x8*)&KET[((size_t)(b*NPIX) + n0 + j*16 + lr)*64 + kt*32 + lk];
    #pragma unroll
    for (int r=0;r<4;r++){
      bf16x8 a = *(const bf16x8*)&ATT[((size_t)(b*CIN) + w*64 + r*16 + lr)*64 + kt*32 + lk];
      #pragma unroll
      for (int j=0;j<4;j++)
        acc[r][j] = MFMA(a, bb[j], acc[r][j]);
    }
  }
  int rq = (lane>>4)<<2;
  // two passes: pass p handles rows p*256 .. p*256+255 (waves 4p..4p+3)
  #pragma unroll
  for (int pass=0; pass<2; pass++){
    __syncthreads();
    if ((w>>2) == pass){
      int wl = w & 3;
      #pragma unroll
      for (int r=0;r<4;r++)
        #pragma unroll
        for (int j=0;j<4;j++)
          #pragma unroll
          for (int q=0;q<4;q++)
            CT[(wl*64 + r*16 + rq + q)*66 + j*16 + lr] = acc[r][j][q];
    }
    __syncthreads();
    // stream: thread i -> (row = i>>2, 16 consecutive f32 at seg)
    #pragma unroll
    for (int i0=0; i0<2; i0++){
      int i = i0*512 + tid;
      int row = i >> 2, seg = (i & 3)*16;
      size_t gidx = ((size_t)(b*CIN) + pass*256 + row)*NPIX + n0 + seg;
      const float* cp = &CT[row*66 + seg];
      const float* xp = &x[gidx];
      float* op = &out[gidx];
      #pragma unroll
      for (int u=0;u<4;u++){
        f32x4 c4 = *(const f32x4*)(cp + u*4);
        f32x4 x4 = *(const f32x4*)(xp + u*4);
        *(f32x4*)(op + u*4) = c4 + x4;
      }
    }
  }
}

extern "C" void kernel_launch(void* const* d_in, const int* in_sizes, int n_in,
                              void* d_out, int out_size, void* d_ws, size_t ws_size,
                              hipStream_t stream){
  const float* x   = (const float*)d_in[0];
  const float* Wq  = (const float*)d_in[1];
  const float* bq  = (const float*)d_in[2];
  const float* Wk  = (const float*)d_in[3];
  const float* bk  = (const float*)d_in[4];
  const float* Wv  = (const float*)d_in[5];
  const float* bv  = (const float*)d_in[6];
  const float* Wsq = (const float*)d_in[7];
  const float* bsq = (const float*)d_in[8];
  const float* We  = (const float*)d_in[9];
  const float* be  = (const float*)d_in[10];
  float* out = (float*)d_out;

  char* wsb = (char*)d_ws;
  size_t off = 0;
  auto alloc = [&](size_t bytes)->void*{
    void* p = wsb + off; off += (bytes + 255) & ~(size_t)255; return p;
  };
  short* WALL2= (short*)alloc((size_t)768*512*2);
  float* BSE  = (float*)alloc(128*4);
  float* VV   = (float*)alloc(512*4);
  float* DD   = (float*)alloc(256);
  short* XT2  = (short*)alloc((size_t)BATCH*NPIX*512*2);
  float* QKacc= (float*)alloc((size_t)BATCH*NPIX*4);
  float* GATE = (float*)alloc((size_t)BATCH*NPIX*4);
  float* QSR  = (float*)alloc((size_t)BATCH*64*NPIX*4);
  short* KET  = (short*)alloc((size_t)BATCH*NPIX*64*2);
  float* Mb   = (float*)alloc((size_t)BATCH*512*64*4);
  float* Sb   = (float*)alloc((size_t)BATCH*64*4);
  float* EN   = (float*)alloc((size_t)BATCH*512*64*4);
  short* ATT  = (short*)alloc((size_t)BATCH*512*64*2);

  k_convw  <<<1536, 256, 0, stream>>>(Wq,bq,Wk,bk,Wsq,bsq,We,be, WALL2,BSE,VV,DD,
                                      QKacc, Mb);
  k_stage  <<<dim3(8,64,16), 256, 0, stream>>>(x, VV, XT2, QKacc);
  k_gemm12 <<<dim3(32,6,16), 256, 0, stream>>>(WALL2, XT2, BSE, QKacc, QSR, KET);
  k_gate   <<<256, 256, 0, stream>>>(QKacc, DD, GATE);
  k_S      <<<dim3(64,16), 256, 0, stream>>>(QSR, GATE, Sb);
  k_M      <<<dim3(16,16), 512, 0, stream>>>(x, QSR, GATE, Mb);
  k_energy <<<dim3(16,16), 256, 0, stream>>>(Wv, bv, Mb, Sb, EN);
  k_softmax<<<2048, 256, 0, stream>>>(EN, ATT);
  k_out    <<<dim3(64,16), 512, 0, stream>>>(x, ATT, KET, out);
}

// Round 17
// 279.075 us; speedup vs baseline: 1.0257x; 1.0257x over previous
//
#include <hip/hip_runtime.h>

#define BATCH 16
#define CIN 512
#define NPIX 4096

typedef __attribute__((ext_vector_type(8))) short bf16x8;
typedef __attribute__((ext_vector_type(4))) float f32x4;

#define MFMA(a,b,c) __builtin_amdgcn_mfma_f32_16x16x32_bf16((a),(b),(c),0,0,0)

// async global->LDS DMA, 16B/lane, dst = wave-uniform base (+ HW lane*16)
#define GLOAD(g, l) __builtin_amdgcn_global_load_lds( \
    (const __attribute__((address_space(1))) unsigned int*)(g), \
    (__attribute__((address_space(3))) unsigned int*)(l), 16, 0, 0)

union PK  { short s[8]; bf16x8 v; };
union PK4 { short s[4]; uint2 u; };

__device__ __forceinline__ unsigned short bf16_rne(float f){
  unsigned u = __float_as_uint(f);
  return (unsigned short)((u + 0x7fffu + ((u >> 16) & 1u)) >> 16);
}
__device__ __forceinline__ void f32_split(float f, short &h, short &l){
  unsigned short hu = bf16_rne(f);
  h = (short)hu;
  float fh = __uint_as_float((unsigned)hu << 16);
  l = (short)bf16_rne(f - fh);
}
__device__ __forceinline__ void split8(float4 a, float4 b, bf16x8 &h, bf16x8 &l){
  float vv[8] = {a.x,a.y,a.z,a.w,b.x,b.y,b.z,b.w};
  PK ph, pl;
  #pragma unroll
  for (int z=0;z<8;z++){ short hh,ll; f32_split(vv[z],hh,ll); ph.s[z]=hh; pl.s[z]=ll; }
  h = ph.v; l = pl.v;
}

// full-spread chunk swizzle: pos = chunk ^ ((r ^ (r>>2)) & 3)  -> 2-way banks max
__device__ __forceinline__ int swz4(int r){ return (r ^ (r >> 2)) & 3; }

// ---------------- weight convert + gate-algebra precompute + ws zeroing ----------------
// WALL2 [16 kt][768 rows][32 k] bf16, chunk^swz4(row) baked in:
//   rows 0-511: interleaved QK-hi (2o=Wq, 2o+1=Wk); 512-575 Ws-hi; 576-639 Ws-lo;
//   640-703 We-hi; 704-767 zero-pad.
// VV[512] = Wk^T bq + Wq^T bk (f32); DD[0] = bq.bk; BSE[128] = {bs, be}.
__global__ __launch_bounds__(256)
void k_convw(const float* __restrict__ Wq, const float* __restrict__ bq,
             const float* __restrict__ Wk, const float* __restrict__ bk,
             const float* __restrict__ Ws, const float* __restrict__ bs,
             const float* __restrict__ We, const float* __restrict__ be,
             short* __restrict__ WALL2, float* __restrict__ BSE,
             float* __restrict__ VV, float* __restrict__ DD,
             float* __restrict__ QKacc, float* __restrict__ Mb,
             float* __restrict__ Sb){
  int t = blockIdx.x*256 + threadIdx.x;   // t < 768*512
  if (t < 768*512){
    int r = t >> 9, k = t & 511;
    float v;
    short out;
    if (r < 512){
      v = (r & 1) ? Wk[(r>>1)*512 + k] : Wq[(r>>1)*512 + k];
      out = (short)bf16_rne(v);
    } else if (r < 576){
      short h,l; f32_split(Ws[(r-512)*512 + k], h, l); out = h;
    } else if (r < 640){
      short h,l; f32_split(Ws[(r-576)*512 + k], h, l); out = l;
    } else if (r < 704){
      out = (short)bf16_rne(We[(r-640)*512 + k]);
    } else {
      out = 0;
    }
    int kt = k >> 5, lc = (k >> 3) & 3, e = k & 7;
    int pc = lc ^ swz4(r);
    WALL2[((size_t)kt*768 + r)*32 + pc*8 + e] = out;
  }
  if (t < 128) BSE[t] = (t < 64) ? bs[t] : be[t-64];
  if (t < 512){
    float a = 0.f;
    for (int o=0;o<256;o++) a += bq[o]*Wk[o*512+t] + bk[o]*Wq[o*512+t];
    VV[t] = a;
  }
  if (t == 0){
    float a = 0.f;
    for (int o=0;o<256;o++) a += bq[o]*bk[o];
    DD[0] = a;
  }
  // zero accumulation buffers
  for (int i = t; i < BATCH*NPIX; i += 1536*256) QKacc[i] = 0.f;
  for (int i = t; i < BATCH*512*64; i += 1536*256) Mb[i] = 0.f;
  if (t < BATCH*64) Sb[t] = 0.f;
}

// ---------------- x pack: XT2[b][nt 32][kt 16][128 n][32 k] bf16, swizzled ----------------
// Also folds v.x into QKacc (exact f32).
__global__ __launch_bounds__(256)
void k_stage(const float* __restrict__ x, const float* __restrict__ VV,
             short* __restrict__ XT2, float* __restrict__ QKacc){
  __shared__ float XF[64*65];
  int cb = blockIdx.x, nb = blockIdx.y, b = blockIdx.z;
  int tid = threadIdx.x;
  {
    int cc = tid >> 2, ni = (tid & 3) * 16;
    const float* xp = x + ((size_t)(b*CIN + cb*64 + cc))*NPIX + nb*64 + ni;
    #pragma unroll
    for (int u=0;u<16;u+=4){
      float4 v = *(const float4*)(xp + u);
      XF[cc*65 + ni+u+0] = v.x; XF[cc*65 + ni+u+1] = v.y;
      XF[cc*65 + ni+u+2] = v.z; XF[cc*65 + ni+u+3] = v.w;
    }
  }
  __syncthreads();
  {
    int nn = tid >> 2, cs = tid & 3;
    int nl = (nb & 1)*64 + nn, nt = nb >> 1;
    int kt = cb*2 + (cs >> 1);
    float pa = 0.f;
    PK c0, c1;
    #pragma unroll
    for (int i=0;i<8;i++){
      float f = XF[(cs*16 + i)*65 + nn];
      pa += VV[cb*64 + cs*16 + i] * f;
      c0.s[i] = (short)bf16_rne(f);
    }
    #pragma unroll
    for (int i=0;i<8;i++){
      float f = XF[(cs*16 + 8 + i)*65 + nn];
      pa += VV[cb*64 + cs*16 + 8 + i] * f;
      c1.s[i] = (short)bf16_rne(f);
    }
    short* rowb = XT2 + ((((size_t)(b*32 + nt))*16 + kt)*128 + nl)*32;
    int pc0 = ((cs & 1)*2 + 0) ^ swz4(nl);
    int pc1 = ((cs & 1)*2 + 1) ^ swz4(nl);
    *(bf16x8*)&rowb[pc0*8] = c0.v;
    *(bf16x8*)&rowb[pc1*8] = c1.v;
    pa += __shfl_xor(pa, 1);
    pa += __shfl_xor(pa, 2);
    if ((tid & 3) == 0)
      atomicAdd(&QKacc[(size_t)b*NPIX + nb*64 + nn], pa);
  }
}

// ---------------- fused gemm: all 768 A-rows, one dispatch wave ----------------
// grid (32 nt, 6 mt, 16 b), 256 thr, m97 anatomy (dbuf GLOAD A+B, acc[4][4]).
// mt 0-3: QK pair-product -> QKacc. mt 4: Qs hi|lo -> QSR (un-gated). mt 5: Ke -> KET.
__global__ __launch_bounds__(256)
void k_gemm12(const short* __restrict__ WALL2, const short* __restrict__ XT2,
              const float* __restrict__ BSE,
              float* __restrict__ QKacc, float* __restrict__ QSR,
              short* __restrict__ KET){
  __shared__ __align__(16) char SMEM[32768];
  short (*As)[128*32] = (short(*)[128*32])SMEM;            // 2 x 8KB
  short (*Bs)[128*32] = (short(*)[128*32])(SMEM + 16384);  // 2 x 8KB
  __shared__ float QKp[2][2][4][16];
  int nt = blockIdx.x, mt = blockIdx.y, b = blockIdx.z;
  int tid = threadIdx.x, w = tid>>6, lane = tid&63;
  int lr = lane&15, cg = lane>>4;
  int rh = w>>1, nh = w&1;
  const char* Abase = (const char*)WALL2 + (size_t)mt*128*64;
  const char* Bbase = (const char*)XT2 + ((size_t)(b*32 + nt)*16)*8192;
  #pragma unroll
  for (int i=0;i<2;i++){
    GLOAD(Abase + (i*256+tid)*16, ((char*)&As[0][0]) + (i*256+(tid&~63))*16);
    GLOAD(Bbase + (i*256+tid)*16, ((char*)&Bs[0][0]) + (i*256+(tid&~63))*16);
  }
  f32x4 acc[4][4] = {};
  int swz = ((cg ^ swz4(lr)) << 3);        // 2-way banks (free) vs old 4-way
  for (int kt=0; kt<16; kt++){
    int cur = kt & 1;
    __syncthreads();
    if (kt < 15){
      const char* An = Abase + (size_t)(kt+1)*768*64;
      const char* Bn = Bbase + (size_t)(kt+1)*8192;
      #pragma unroll
      for (int i=0;i<2;i++){
        GLOAD(An + (i*256+tid)*16, ((char*)&As[cur^1][0]) + (i*256+(tid&~63))*16);
        GLOAD(Bn + (i*256+tid)*16, ((char*)&Bs[cur^1][0]) + (i*256+(tid&~63))*16);
      }
    }
    bf16x8 a[4], bb[4];
    #pragma unroll
    for (int m=0;m<4;m++) a[m] = *(const bf16x8*)&As[cur][(rh*64 + m*16 + lr)*32 + swz];
    #pragma unroll
    for (int j=0;j<4;j++) bb[j] = *(const bf16x8*)&Bs[cur][(nh*64 + j*16 + lr)*32 + swz];
    #pragma unroll
    for (int m=0;m<4;m++)
      #pragma unroll
      for (int j=0;j<4;j++)
        acc[m][j] = MFMA(a[m], bb[j], acc[m][j]);
  }
  __syncthreads();                          // k-loop LDS reads done
  int rq = (lane>>4)<<2;
  if (mt < 4){
    // pair product: regs (0,1),(2,3) = consecutive rows = (Q,K) of a pair
    float p[4] = {0.f,0.f,0.f,0.f};
    #pragma unroll
    for (int m=0;m<4;m++)
      #pragma unroll
      for (int j=0;j<4;j++){
        f32x4 a4 = acc[m][j];
        p[j] += a4[0]*a4[1] + a4[2]*a4[3];
      }
    #pragma unroll
    for (int j=0;j<4;j++){ p[j] += __shfl_xor(p[j],16); p[j] += __shfl_xor(p[j],32); }
    if (lane < 16){
      #pragma unroll
      for (int j=0;j<4;j++) QKp[rh][nh][j][lane] = p[j];
    }
    __syncthreads();
    if (rh == 0 && lane < 16){
      #pragma unroll
      for (int j=0;j<4;j++){
        float v = QKp[0][nh][j][lane] + QKp[1][nh][j][lane];
        atomicAdd(&QKacc[(size_t)b*NPIX + nt*128 + nh*64 + j*16 + lane], v);
      }
    }
  } else if (mt == 4){
    // Qs: rh=1 holds lo rows -> LDS handoff; rh=0 combines + bs, writes QSR (no gate)
    float* LO = (float*)SMEM;               // [nh][o 64][nl 64] f32 = 32KB
    if (rh == 1){
      #pragma unroll
      for (int m=0;m<4;m++)
        #pragma unroll
        for (int j=0;j<4;j++)
          #pragma unroll
          for (int q=0;q<4;q++)
            LO[nh*4096 + (m*16 + rq + q)*64 + j*16 + lr] = acc[m][j][q];
    }
    __syncthreads();
    if (rh == 0){
      #pragma unroll
      for (int m=0;m<4;m++){
        int o0 = m*16 + rq;
        f32x4 bs4 = *(const f32x4*)&BSE[o0];
        #pragma unroll
        for (int j=0;j<4;j++){
          int n = nt*128 + nh*64 + j*16 + lr;
          #pragma unroll
          for (int q=0;q<4;q++)
            QSR[((size_t)(b*64) + o0 + q)*NPIX + n] =
                acc[m][j][q] + LO[nh*4096 + (o0+q)*64 + j*16 + lr] + bs4[q];
        }
      }
    }
  } else {
    // Ke: rh=0 rows are We (d 0-63); rh=1 is pad (discard)
    if (rh == 0){
      #pragma unroll
      for (int m=0;m<4;m++){
        int d0 = m*16 + rq;
        f32x4 be4 = *(const f32x4*)&BSE[64 + d0];
        #pragma unroll
        for (int j=0;j<4;j++){
          int n = nt*128 + nh*64 + j*16 + lr;
          PK4 pk;
          #pragma unroll
          for (int q=0;q<4;q++) pk.s[q] = (short)bf16_rne(acc[m][j][q] + be4[q]);
          *(uint2*)&KET[((size_t)(b*NPIX) + n)*64 + d0] = pk.u;
        }
      }
    }
  }
}

// ---------------- gate ----------------
__global__ __launch_bounds__(256)
void k_gate(const float* __restrict__ QKacc, const float* __restrict__ DD,
            float* __restrict__ GATE){
  int i = blockIdx.x*256 + threadIdx.x;
  GATE[i] = 1.f/(1.f + __expf(-(QKacc[i] + DD[0]) * (1.f/256.f)));
}

// ---------------- M += x.(QSR*g)^T over n; S folded in (w0 reduces B-row sums) ----------------
__global__ __launch_bounds__(512)
void k_M(const float* __restrict__ x, const float* __restrict__ QSR,
         const float* __restrict__ GATE, float* __restrict__ M,
         float* __restrict__ S){
  int slab = blockIdx.x, b = blockIdx.y;   // 16 slabs x 256 n
  int tid = threadIdx.x, w = tid>>6, lane = tid&63;
  int lr = lane&15, lk8 = (lane>>4)<<3;
  f32x4 acc[4][4] = {};
  float srow[4] = {0.f,0.f,0.f,0.f};
  for (int kt=0; kt<8; kt++){
    int noff = slab*256 + kt*32 + lk8;
    const float* gp = GATE + (size_t)b*NPIX + noff;
    float4 g0 = *(const float4*)gp;
    float4 g1 = *(const float4*)(gp + 4);
    bf16x8 bh[4], bl[4];
    #pragma unroll
    for (int j=0;j<4;j++){
      const float* qp = QSR + ((size_t)(b*64) + j*16 + lr)*NPIX + noff;
      float4 q0 = *(const float4*)qp;
      float4 q1 = *(const float4*)(qp+4);
      q0.x *= g0.x; q0.y *= g0.y; q0.z *= g0.z; q0.w *= g0.w;
      q1.x *= g1.x; q1.y *= g1.y; q1.z *= g1.z; q1.w *= g1.w;
      srow[j] += q0.x+q0.y+q0.z+q0.w + q1.x+q1.y+q1.z+q1.w;
      split8(q0, q1, bh[j], bl[j]);
    }
    #pragma unroll
    for (int r=0;r<4;r++){
      const float* xp = x + ((size_t)(b*CIN) + w*64 + r*16 + lr)*NPIX + noff;
      bf16x8 ah, al;
      split8(*(const float4*)xp, *(const float4*)(xp+4), ah, al);
      #pragma unroll
      for (int j=0;j<4;j++){
        acc[r][j] = MFMA(al, bh[j], acc[r][j]);
        acc[r][j] = MFMA(ah, bl[j], acc[r][j]);
        acc[r][j] = MFMA(ah, bh[j], acc[r][j]);
      }
    }
  }
  // S contribution: every wave computed identical srow (B shared) -> only w0 commits
  if (w == 0){
    #pragma unroll
    for (int j=0;j<4;j++){
      float v = srow[j];
      v += __shfl_xor(v, 16);
      v += __shfl_xor(v, 32);
      if (lane < 16) atomicAdd(&S[b*64 + j*16 + lane], v);
    }
  }
  int rq = (lane>>4)<<2;
  #pragma unroll
  for (int r=0;r<4;r++)
    #pragma unroll
    for (int j=0;j<4;j++)
      #pragma unroll
      for (int q=0;q<4;q++)
        atomicAdd(&M[((size_t)(b*CIN) + w*64 + r*16 + rq + q)*64 + j*16 + lr], acc[r][j][q]);
}

// ---------------- energy = Wv(f32) . M + bv*S  (VALU, exact) ----------------
__global__ __launch_bounds__(256)
void k_energy(const float* __restrict__ Wv, const float* __restrict__ bv,
              const float* __restrict__ M, const float* __restrict__ S,
              float* __restrict__ EN){
  __shared__ __align__(16) float ML[128*68];
  int cch = blockIdx.x, b = blockIdx.y;
  int tid = threadIdx.x;
  int d4 = tid & 15, ci = tid >> 4;
  f32x4 acc[2] = {};
  for (int kt=0; kt<4; kt++){
    __syncthreads();
    for (int i = tid; i < 2048; i += 256){
      int k = i >> 4, c4 = (i & 15) * 4;
      *(float4*)&ML[k*68 + c4] = *(const float4*)&M[((size_t)(b*CIN) + kt*128 + k)*64 + c4];
    }
    __syncthreads();
    #pragma unroll
    for (int m=0;m<2;m++){
      int c = cch*32 + ci + 16*m;
      const float* wvp = Wv + (size_t)c*512 + kt*128;
      for (int k4=0;k4<32;k4++){
        float4 wv4 = *(const float4*)(wvp + k4*4);
        f32x4 m0 = *(const f32x4*)&ML[(k4*4+0)*68 + d4*4];
        f32x4 m1 = *(const f32x4*)&ML[(k4*4+1)*68 + d4*4];
        f32x4 m2 = *(const f32x4*)&ML[(k4*4+2)*68 + d4*4];
        f32x4 m3 = *(const f32x4*)&ML[(k4*4+3)*68 + d4*4];
        acc[m] += m0*wv4.x + m1*wv4.y + m2*wv4.z + m3*wv4.w;
      }
    }
  }
  f32x4 s4 = *(const f32x4*)&S[b*64 + d4*4];
  #pragma unroll
  for (int m=0;m<2;m++){
    int c = cch*32 + ci + 16*m;
    f32x4 r = acc[m] + s4*bv[c];
    *(f32x4*)&EN[((size_t)(b*CIN) + c)*64 + d4*4] = r;
  }
}

// ---------------- softmax over d=64 ----------------
__global__ __launch_bounds__(256)
void k_softmax(const float* __restrict__ EN, short* __restrict__ ATT){
  int row = blockIdx.x*4 + (threadIdx.x>>6);
  int lane = threadIdx.x & 63;
  float v = EN[(size_t)row*64 + lane];
  float m = v;
  #pragma unroll
  for (int s=1;s<64;s<<=1) m = fmaxf(m, __shfl_xor(m, s));
  float e = __expf(v - m);
  float sum = e;
  #pragma unroll
  for (int s=1;s<64;s<<=1) sum += __shfl_xor(sum, s);
  ATT[(size_t)row*64 + lane] = (short)bf16_rne(e / sum);
}

// ---------------- out = x + attn . Ke (LDS-transposed epilogue: 256B granules) ----------------
__global__ __launch_bounds__(512)
void k_out(const float* __restrict__ x, const short* __restrict__ ATT,
           const short* __restrict__ KET, float* __restrict__ out){
  __shared__ __align__(16) float CT[256*66];   // 67.6 KB, stride 66 breaks conflicts
  int nt = blockIdx.x, b = blockIdx.y;
  int n0 = nt*64;
  int tid = threadIdx.x, w = tid>>6, lane = tid&63;
  int lr = lane&15, lk = (lane>>4)<<3;
  f32x4 acc[4][4] = {};
  #pragma unroll
  for (int kt=0; kt<2; kt++){
    bf16x8 bb[4];
    #pragma unroll
    for (int j=0;j<4;j++)
      bb[j] = *(const bf16x8*)&KET[((size_t)(b*NPIX) + n0 + j*16 + lr)*64 + kt*32 + lk];
    #pragma unroll
    for (int r=0;r<4;r++){
      bf16x8 a = *(const bf16x8*)&ATT[((size_t)(b*CIN) + w*64 + r*16 + lr)*64 + kt*32 + lk];
      #pragma unroll
      for (int j=0;j<4;j++)
        acc[r][j] = MFMA(a, bb[j], acc[r][j]);
    }
  }
  int rq = (lane>>4)<<2;
  // two passes: pass p handles rows p*256 .. p*256+255 (waves 4p..4p+3)
  #pragma unroll
  for (int pass=0; pass<2; pass++){
    __syncthreads();
    if ((w>>2) == pass){
      int wl = w & 3;
      #pragma unroll
      for (int r=0;r<4;r++)
        #pragma unroll
        for (int j=0;j<4;j++)
          #pragma unroll
          for (int q=0;q<4;q++)
            CT[(wl*64 + r*16 + rq + q)*66 + j*16 + lr] = acc[r][j][q];
    }
    __syncthreads();
    // stream: thread i -> (row = i>>2, 16 consecutive f32 at seg)
    #pragma unroll
    for (int i0=0; i0<2; i0++){
      int i = i0*512 + tid;
      int row = i >> 2, seg = (i & 3)*16;
      size_t gidx = ((size_t)(b*CIN) + pass*256 + row)*NPIX + n0 + seg;
      const float* cp = &CT[row*66 + seg];
      const float* xp = &x[gidx];
      float* op = &out[gidx];
      #pragma unroll
      for (int u=0;u<4;u++){
        f32x4 c4 = *(const f32x4*)(cp + u*4);
        f32x4 x4 = *(const f32x4*)(xp + u*4);
        *(f32x4*)(op + u*4) = c4 + x4;
      }
    }
  }
}

extern "C" void kernel_launch(void* const* d_in, const int* in_sizes, int n_in,
                              void* d_out, int out_size, void* d_ws, size_t ws_size,
                              hipStream_t stream){
  const float* x   = (const float*)d_in[0];
  const float* Wq  = (const float*)d_in[1];
  const float* bq  = (const float*)d_in[2];
  const float* Wk  = (const float*)d_in[3];
  const float* bk  = (const float*)d_in[4];
  const float* Wv  = (const float*)d_in[5];
  const float* bv  = (const float*)d_in[6];
  const float* Wsq = (const float*)d_in[7];
  const float* bsq = (const float*)d_in[8];
  const float* We  = (const float*)d_in[9];
  const float* be  = (const float*)d_in[10];
  float* out = (float*)d_out;

  char* wsb = (char*)d_ws;
  size_t off = 0;
  auto alloc = [&](size_t bytes)->void*{
    void* p = wsb + off; off += (bytes + 255) & ~(size_t)255; return p;
  };
  short* WALL2= (short*)alloc((size_t)768*512*2);
  float* BSE  = (float*)alloc(128*4);
  float* VV   = (float*)alloc(512*4);
  float* DD   = (float*)alloc(256);
  short* XT2  = (short*)alloc((size_t)BATCH*NPIX*512*2);
  float* QKacc= (float*)alloc((size_t)BATCH*NPIX*4);
  float* GATE = (float*)alloc((size_t)BATCH*NPIX*4);
  float* QSR  = (float*)alloc((size_t)BATCH*64*NPIX*4);
  short* KET  = (short*)alloc((size_t)BATCH*NPIX*64*2);
  float* Mb   = (float*)alloc((size_t)BATCH*512*64*4);
  float* Sb   = (float*)alloc((size_t)BATCH*64*4);
  float* EN   = (float*)alloc((size_t)BATCH*512*64*4);
  short* ATT  = (short*)alloc((size_t)BATCH*512*64*2);

  k_convw  <<<1536, 256, 0, stream>>>(Wq,bq,Wk,bk,Wsq,bsq,We,be, WALL2,BSE,VV,DD,
                                      QKacc, Mb, Sb);
  k_stage  <<<dim3(8,64,16), 256, 0, stream>>>(x, VV, XT2, QKacc);
  k_gemm12 <<<dim3(32,6,16), 256, 0, stream>>>(WALL2, XT2, BSE, QKacc, QSR, KET);
  k_gate   <<<256, 256, 0, stream>>>(QKacc, DD, GATE);
  k_M      <<<dim3(16,16), 512, 0, stream>>>(x, QSR, GATE, Mb, Sb);
  k_energy <<<dim3(16,16), 256, 0, stream>>>(Wv, bv, Mb, Sb, EN);
  k_softmax<<<2048, 256, 0, stream>>>(EN, ATT);
  k_out    <<<dim3(64,16), 512, 0, stream>>>(x, ATT, KET, out);
}